// Round 12
// baseline (59.139 us; speedup 1.0000x reference)
//
#include <hip/hip_runtime.h>

// CostVolume via banded-correlation MFMA (v_mfma_f32_16x16x32_f16).
// cost[b,h,w,(sh+4)*9+(sw+4)] = LeakyReLU_0.1( mean_c x1[b,h,w,c]*warped[b,h+sh,w+sw,c] )
// B=8 H=128 W=192 C=128, MD=4. Output fp32 [B,H,W,81].
//
// Round-12: R11 (55.3us) with the validated MLP lever pushed to its end.
//  1. Depth-3 staging sets (gpA/gpB/gpC, +12 VGPR): c0,c1,c2 issued
//     back-to-back at block start BEFORE any commit; c3 issued at step0
//     into the recycled gpA. Three 49KB bursts in flight during the
//     prologue, 1-2 throughout the loop.
//  2. x1 fully preconverted in prologue (afr[4], 16 regs): steady-state
//     steps are pure {barrier; ds_write; 18 ds_read + 18 MFMA} with no
//     global issue or pack VALU in the dependence chain.
//  3. Epilogue LeakyReLU as fmaxf(v, 0.1f*v): bitwise-identical to the
//     ?: form for all finite v, one fewer VALU op per output.
// Reg budget: ~84 arch + 72 AGPR = 156 <= 170 -> 3 waves/SIMD under
// lb(512,4) (the R6/R9 21.6% collapses were lb(,3) artifacts -- confirmed
// across 7 builds: lb4 => ~40%, lb3 => ~21.6%).
// Lessons honored: lb4 load-bearing; band stores stay a tight per-tile
// burst (R10); no halo amplification (R1/R5); staging layout + store runs
// + reg budget co-designed (R7).
// Everything else byte-identical to R4/R11: 8x16 tile, 8 waves, RH=16
// swizzled conflict-free staging, lgkm-only barriers, XCD swizzle
// (192 wg = one image per XCD), direct band stores (WRITE == ideal).

namespace {
constexpr int Bb = 8, Hh = 128, Ww = 192, Cn = 128;
constexpr int MDc = 4;
constexpr int TH = 8, TWT = 16;        // block tile: 8 rows x 16 px
constexpr int NTHR = 512;              // 8 waves
constexpr int RH = 16;                 // staged warped rows  (h0-4 .. h0+11)
constexpr int RPX = 24;                // staged warped px    (w0-4 .. w0+19)
constexpr int KC = 32;                 // channels per chunk
constexpr int NCH = Cn / KC;           // 4
constexpr int KQB = RPX * 16;          // 384 B per kq-plane (24 x 16B slots)
constexpr int ROWB = 4 * KQB;          // 1536 B per staged row
constexpr int BUFB = RH * ROWB;        // 24576 B per buffer
constexpr int RUNS = RH * RPX * 4;     // 1536 8-channel runs per chunk
constexpr int NIT = RUNS / NTHR;       // 3
constexpr float NEG = 0.1f;
}

typedef __fp16 h2v   __attribute__((ext_vector_type(2)));
typedef __fp16 f16x8 __attribute__((ext_vector_type(8)));
typedef float  f32x4 __attribute__((ext_vector_type(4)));

__device__ __forceinline__ unsigned pkh2(float a, float b) {
    h2v h = __builtin_amdgcn_cvt_pkrtz(a, b);
    return __builtin_bit_cast(unsigned, h);
}

// Barrier with LDS-only drain: global prefetch loads stay in flight across it.
__device__ __forceinline__ void barrier_lgkm() {
    asm volatile("s_waitcnt lgkmcnt(0)\n\ts_barrier" ::: "memory");
}

__global__ __launch_bounds__(NTHR, 4)
void costvol_mfma(const float* __restrict__ x1,
                  const float* __restrict__ wp,
                  float* __restrict__ out)
{
    __shared__ __align__(16) unsigned char smem[2 * BUFB];   // 48 KiB

    const int tid  = threadIdx.x;
    const int wv   = tid >> 6;        // 0..7 : h-row within stripe
    const int lane = tid & 63;
    const int nI   = lane & 15;       // A-row m / B-col n lane index
    const int kq   = lane >> 4;       // 0..3 : k-group (8 channels each)

    // XCD swizzle: 1536 wg = 8 XCDs x 192; 192 = one batch image (12x16).
    const int id = blockIdx.x;
    const int wg = (id & 7) * 192 + (id >> 3);
    const int bx = wg % 12;
    const int t2 = wg / 12;
    const int by = t2 & 15;
    const int bz = t2 >> 4;

    const int w0 = bx * TWT;
    const int h0 = by * TH;
    const int b  = bz;

    // ---- warped staging decode: run = (row, px, kq), kq innermost ----
    int g_off[NIT]; int l_off[NIT]; bool g_ok[NIT];
#pragma unroll
    for (int it = 0; it < NIT; ++it) {
        int s   = tid + it * NTHR;    // 0..1535
        int skq = s & 3;
        int t   = s >> 2;             // 0..383
        int px  = t % RPX;
        int row = t / RPX;
        int hw  = h0 - MDc + row;
        int ww  = w0 - MDc + px;
        bool ok = (unsigned)hw < (unsigned)Hh && (unsigned)ww < (unsigned)Ww;
        g_ok[it]  = ok;
        g_off[it] = ((b * Hh + (ok ? hw : 0)) * Ww + (ok ? ww : 0)) * Cn + skq * 8;
        l_off[it] = row * ROWB + skq * KQB + ((px ^ (skq << 1)) * 16);
    }

    // Three independent staging register sets (depth-3 in-flight bursts).
    uint4 gpA[NIT], gpB[NIT], gpC[NIT];
#define MAKE_LOAD(NAME, REGS)                                                  \
    auto NAME = [&](int ch) {                                                  \
        _Pragma("unroll")                                                      \
        for (int it = 0; it < NIT; ++it) {                                     \
            if (g_ok[it]) {                                                    \
                const float* p = wp + g_off[it] + ch * KC;                     \
                float4 u = *reinterpret_cast<const float4*>(p);                \
                float4 v = *reinterpret_cast<const float4*>(p + 4);            \
                REGS[it] = make_uint4(pkh2(u.x, u.y), pkh2(u.z, u.w),          \
                                      pkh2(v.x, v.y), pkh2(v.z, v.w));         \
            } else {                                                           \
                REGS[it] = make_uint4(0u, 0u, 0u, 0u);                         \
            }                                                                  \
        }                                                                      \
    }
#define MAKE_WRITE(NAME, REGS)                                                 \
    auto NAME = [&](int buf) {                                                 \
        _Pragma("unroll")                                                      \
        for (int it = 0; it < NIT; ++it)                                       \
            *reinterpret_cast<uint4*>(smem + buf * BUFB + l_off[it]) = REGS[it]; \
    }
    MAKE_LOAD(LOADA, gpA);  MAKE_WRITE(WRITEA, gpA);
    MAKE_LOAD(LOADB, gpB);  MAKE_WRITE(WRITEB, gpB);
    MAKE_LOAD(LOADC, gpC);  MAKE_WRITE(WRITEC, gpC);
#undef MAKE_LOAD
#undef MAKE_WRITE

    // ---- prologue: issue c0,c1,c2 back-to-back (3 bursts in flight),
    //      then all x1 loads + preconvert, then commit c0.
    LOADA(0);
    LOADB(1);
    LOADC(2);

    const float* xp = x1 + ((size_t)((b * Hh + h0 + wv) * Ww) + w0 + nI) * Cn + kq * 8;
    uint4 afr[NCH];
#pragma unroll
    for (int ch = 0; ch < NCH; ++ch) {
        float4 u = *reinterpret_cast<const float4*>(xp + ch * KC);
        float4 v = *reinterpret_cast<const float4*>(xp + ch * KC + 4);
        afr[ch] = make_uint4(pkh2(u.x, u.y), pkh2(u.z, u.w),
                             pkh2(v.x, v.y), pkh2(v.z, v.w));
    }

    f32x4 ac0[9], ac1[9];
#pragma unroll
    for (int s = 0; s < 9; ++s) {
        f32x4 z = {0.f, 0.f, 0.f, 0.f};
        ac0[s] = z; ac1[s] = z;
    }

    // per-lane B fragment offset within a staged row; tile1 = ro0 + 128
    const int ro0 = kq * KQB + ((nI ^ (kq << 1)) * 16);

    WRITEA(0);       // commit c0 -> buf0 (c1,c2,x1 issue time covered latency)

    int cur = 0;
#pragma unroll
    for (int ch = 0; ch < NCH; ++ch) {
        barrier_lgkm();
        // commit chunk ch+1 into the other buffer; c3 issued at step0
        if (ch == 0) { WRITEB(1); LOADA(3); }   // c1 -> buf1; c3 spans steps 0..2
        if (ch == 1) { WRITEC(0); }             // c2 -> buf0
        if (ch == 2) { WRITEA(1); }             // c3 -> buf1
        f16x8 av = __builtin_bit_cast(f16x8, afr[ch]);
        const unsigned char* base = smem + cur * BUFB;
#pragma unroll
        for (int sh = 0; sh < 9; ++sh) {
            const unsigned char* rp = base + (wv + sh) * ROWB;   // staged row ly+sh
            uint4 b0 = *reinterpret_cast<const uint4*>(rp + ro0);
            uint4 b1 = *reinterpret_cast<const uint4*>(rp + ro0 + 128);
            ac0[sh] = __builtin_amdgcn_mfma_f32_16x16x32_f16(
                av, __builtin_bit_cast(f16x8, b0), ac0[sh], 0, 0, 0);
            ac1[sh] = __builtin_amdgcn_mfma_f32_16x16x32_f16(
                av, __builtin_bit_cast(f16x8, b1), ac1[sh], 0, 0, 0);
        }
        cur ^= 1;
    }

    // ---- direct band stores: no LDS round-trip, no barriers ----
    // C/D map: col=n=lane&15, row=m=(lane>>4)*4+reg
    // tile0: staged px p = nI      -> (m, sw4 = nI-m),   valid d=nI-m in [0,8]
    // tile1: staged px p = nI + 8  -> (m, sw4 = nI-m+8), valid d in [-8,0] && nI>=8
    // out k-index = sh*9 + sw4. Active lanes per (rg,sh,tile) write 4
    // contiguous 36B runs (one per kq) -> merged to full lines in L2.
    // LeakyReLU as fmaxf(v, 0.1v): identical result, 1 fewer VALU op.
    const float sc = 1.0f / (float)Cn;
    const size_t rowbase = ((size_t)((b * Hh + h0 + wv) * Ww) + w0) * 81;
#pragma unroll
    for (int rg = 0; rg < 4; ++rg) {
        int m = kq * 4 + rg;
        int d = nI - m;
        bool t0 = (d >= 0 && d <= 8);
        bool t1 = (d >= -8 && d <= 0 && nI >= 8);
        size_t mb = rowbase + (size_t)m * 81;
#pragma unroll
        for (int sh = 0; sh < 9; ++sh) {
            if (t0) {
                float v = ac0[sh][rg] * sc;
                out[mb + sh * 9 + d] = fmaxf(v, NEG * v);
            }
            if (t1) {
                float v = ac1[sh][rg] * sc;
                out[mb + sh * 9 + d + 8] = fmaxf(v, NEG * v);
            }
        }
    }
}

extern "C" void kernel_launch(void* const* d_in, const int* in_sizes, int n_in,
                              void* d_out, int out_size, void* d_ws, size_t ws_size,
                              hipStream_t stream) {
    const float* x1 = (const float*)d_in[0];
    const float* wp = (const float*)d_in[1];
    float* out = (float*)d_out;
    dim3 grid(12 * 16 * 8, 1, 1);   // 1536 blocks, XCD-swizzled in-kernel
    costvol_mfma<<<grid, NTHR, 0, stream>>>(x1, wp, out);
}

// Round 13
// 56.940 us; speedup vs baseline: 1.0386x; 1.0386x over previous
//
#include <hip/hip_runtime.h>

// CostVolume via banded-correlation MFMA (v_mfma_f32_16x16x32_f16).
// cost[b,h,w,(sh+4)*9+(sw+4)] = LeakyReLU_0.1( mean_c x1[b,h,w,c]*warped[b,h+sh,w+sw,c] )
// B=8 H=128 W=192 C=128, MD=4. Output fp32 [B,H,W,81].
//
// Round-13: R11 (55.3us champion) + two micros.
//  - LeakyReLU as fmaxf(v, 0.1v): bitwise-identical, 1 fewer VALU/output.
//  - s_setprio(1) around the ds_read+MFMA cluster (T5): ~1.6-2 resident
//    blocks per CU sit at different phases; priority lets the compute-phase
//    wave win issue arbitration over the staging-phase block. (R6 carried
//    setprio but was confounded by the lb(,3) occupancy cliff.)
// R12 lesson (2nd confirmation of R6): allocator pins arch VGPRs at 64
// under lb(512,4); schedules needing more live data get silently sunk.
// Depth-2 staging (this kernel) is the feasible max of the MLP lever.
//
// Structure (= R11): 8x16 tile, 8 waves; dual staging sets gpA/gpB --
// c0,c1 issued back-to-back in prologue, c2 before loop, c3 at step0;
// every chunk's load->commit distance >= 1.5-2 steps, two 49KB bursts in
// flight. RH=16 swizzled conflict-free staging, lgkm-only barriers, XCD
// swizzle (192 wg = one image per XCD), rolling x1 raw prefetch, direct
// band stores (WRITE == ideal 63.6MB).

namespace {
constexpr int Bb = 8, Hh = 128, Ww = 192, Cn = 128;
constexpr int MDc = 4;
constexpr int TH = 8, TWT = 16;        // block tile: 8 rows x 16 px
constexpr int NTHR = 512;              // 8 waves
constexpr int RH = 16;                 // staged warped rows  (h0-4 .. h0+11)
constexpr int RPX = 24;                // staged warped px    (w0-4 .. w0+19)
constexpr int KC = 32;                 // channels per chunk
constexpr int NCH = Cn / KC;           // 4
constexpr int KQB = RPX * 16;          // 384 B per kq-plane (24 x 16B slots)
constexpr int ROWB = 4 * KQB;          // 1536 B per staged row
constexpr int BUFB = RH * ROWB;        // 24576 B per buffer
constexpr int RUNS = RH * RPX * 4;     // 1536 8-channel runs per chunk
constexpr int NIT = RUNS / NTHR;       // 3
constexpr float NEG = 0.1f;
}

typedef __fp16 h2v   __attribute__((ext_vector_type(2)));
typedef __fp16 f16x8 __attribute__((ext_vector_type(8)));
typedef float  f32x4 __attribute__((ext_vector_type(4)));

__device__ __forceinline__ unsigned pkh2(float a, float b) {
    h2v h = __builtin_amdgcn_cvt_pkrtz(a, b);
    return __builtin_bit_cast(unsigned, h);
}

// Barrier with LDS-only drain: global prefetch loads stay in flight across it.
__device__ __forceinline__ void barrier_lgkm() {
    asm volatile("s_waitcnt lgkmcnt(0)\n\ts_barrier" ::: "memory");
}

__global__ __launch_bounds__(NTHR, 4)
void costvol_mfma(const float* __restrict__ x1,
                  const float* __restrict__ wp,
                  float* __restrict__ out)
{
    __shared__ __align__(16) unsigned char smem[2 * BUFB];   // 48 KiB

    const int tid  = threadIdx.x;
    const int wv   = tid >> 6;        // 0..7 : h-row within stripe
    const int lane = tid & 63;
    const int nI   = lane & 15;       // A-row m / B-col n lane index
    const int kq   = lane >> 4;       // 0..3 : k-group (8 channels each)

    // XCD swizzle: 1536 wg = 8 XCDs x 192; 192 = one batch image (12x16).
    const int id = blockIdx.x;
    const int wg = (id & 7) * 192 + (id >> 3);
    const int bx = wg % 12;
    const int t2 = wg / 12;
    const int by = t2 & 15;
    const int bz = t2 >> 4;

    const int w0 = bx * TWT;
    const int h0 = by * TH;
    const int b  = bz;

    // ---- warped staging decode: run = (row, px, kq), kq innermost ----
    int g_off[NIT]; int l_off[NIT]; bool g_ok[NIT];
#pragma unroll
    for (int it = 0; it < NIT; ++it) {
        int s   = tid + it * NTHR;    // 0..1535
        int skq = s & 3;
        int t   = s >> 2;             // 0..383
        int px  = t % RPX;
        int row = t / RPX;
        int hw  = h0 - MDc + row;
        int ww  = w0 - MDc + px;
        bool ok = (unsigned)hw < (unsigned)Hh && (unsigned)ww < (unsigned)Ww;
        g_ok[it]  = ok;
        g_off[it] = ((b * Hh + (ok ? hw : 0)) * Ww + (ok ? ww : 0)) * Cn + skq * 8;
        l_off[it] = row * ROWB + skq * KQB + ((px ^ (skq << 1)) * 16);
    }

    // Two independent staging register sets: A = even chunks, B = odd.
    uint4 gpA[NIT], gpB[NIT];
    auto LOADA = [&](int ch) {
#pragma unroll
        for (int it = 0; it < NIT; ++it) {
            if (g_ok[it]) {
                const float* p = wp + g_off[it] + ch * KC;
                float4 u = *reinterpret_cast<const float4*>(p);
                float4 v = *reinterpret_cast<const float4*>(p + 4);
                gpA[it] = make_uint4(pkh2(u.x, u.y), pkh2(u.z, u.w),
                                     pkh2(v.x, v.y), pkh2(v.z, v.w));
            } else {
                gpA[it] = make_uint4(0u, 0u, 0u, 0u);
            }
        }
    };
    auto LOADB = [&](int ch) {
#pragma unroll
        for (int it = 0; it < NIT; ++it) {
            if (g_ok[it]) {
                const float* p = wp + g_off[it] + ch * KC;
                float4 u = *reinterpret_cast<const float4*>(p);
                float4 v = *reinterpret_cast<const float4*>(p + 4);
                gpB[it] = make_uint4(pkh2(u.x, u.y), pkh2(u.z, u.w),
                                     pkh2(v.x, v.y), pkh2(v.z, v.w));
            } else {
                gpB[it] = make_uint4(0u, 0u, 0u, 0u);
            }
        }
    };
    auto WRITEA = [&](int buf) {
#pragma unroll
        for (int it = 0; it < NIT; ++it)
            *reinterpret_cast<uint4*>(smem + buf * BUFB + l_off[it]) = gpA[it];
    };
    auto WRITEB = [&](int buf) {
#pragma unroll
        for (int it = 0; it < NIT; ++it)
            *reinterpret_cast<uint4*>(smem + buf * BUFB + l_off[it]) = gpB[it];
    };

    // ---- prologue: issue c0,c1 back-to-back, then x1, commit c0, issue c2.
    LOADA(0);
    LOADB(1);

    const float* xp = x1 + ((size_t)((b * Hh + h0 + wv) * Ww) + w0 + nI) * Cn + kq * 8;
    float4 ar_u = *reinterpret_cast<const float4*>(xp);
    float4 ar_v = *reinterpret_cast<const float4*>(xp + 4);

    f32x4 ac0[9], ac1[9];
#pragma unroll
    for (int s = 0; s < 9; ++s) {
        f32x4 z = {0.f, 0.f, 0.f, 0.f};
        ac0[s] = z; ac1[s] = z;
    }

    // per-lane B fragment offset within a staged row; tile1 = ro0 + 128
    const int ro0 = kq * KQB + ((nI ^ (kq << 1)) * 16);

    WRITEA(0);       // commit c0 -> buf0 (waits only on gpA's loads)
    LOADA(2);        // c2 in flight across steps 0..1

    int cur = 0;
#pragma unroll
    for (int ch = 0; ch < NCH; ++ch) {
        barrier_lgkm();
        // commit chunk ch+1 into the other buffer; issue chunk ch+3
        if (ch == 0) { WRITEB(1); LOADB(3); }   // c1 -> buf1; c3 spans steps 0..2
        if (ch == 1) { WRITEA(0); }             // c2 -> buf0
        if (ch == 2) { WRITEB(1); }             // c3 -> buf1
        // x1: convert this chunk (loaded last step), issue next chunk
        uint4 afr = make_uint4(pkh2(ar_u.x, ar_u.y), pkh2(ar_u.z, ar_u.w),
                               pkh2(ar_v.x, ar_v.y), pkh2(ar_v.z, ar_v.w));
        if (ch + 1 < NCH) {
            ar_u = *reinterpret_cast<const float4*>(xp + (ch + 1) * KC);
            ar_v = *reinterpret_cast<const float4*>(xp + (ch + 1) * KC + 4);
        }
        f16x8 av = __builtin_bit_cast(f16x8, afr);
        const unsigned char* base = smem + cur * BUFB;
        __builtin_amdgcn_s_setprio(1);
#pragma unroll
        for (int sh = 0; sh < 9; ++sh) {
            const unsigned char* rp = base + (wv + sh) * ROWB;   // staged row ly+sh
            uint4 b0 = *reinterpret_cast<const uint4*>(rp + ro0);
            uint4 b1 = *reinterpret_cast<const uint4*>(rp + ro0 + 128);
            ac0[sh] = __builtin_amdgcn_mfma_f32_16x16x32_f16(
                av, __builtin_bit_cast(f16x8, b0), ac0[sh], 0, 0, 0);
            ac1[sh] = __builtin_amdgcn_mfma_f32_16x16x32_f16(
                av, __builtin_bit_cast(f16x8, b1), ac1[sh], 0, 0, 0);
        }
        __builtin_amdgcn_s_setprio(0);
        cur ^= 1;
    }

    // ---- direct band stores: no LDS round-trip, no barriers ----
    // C/D map: col=n=lane&15, row=m=(lane>>4)*4+reg
    // tile0: staged px p = nI      -> (m, sw4 = nI-m),   valid d=nI-m in [0,8]
    // tile1: staged px p = nI + 8  -> (m, sw4 = nI-m+8), valid d in [-8,0] && nI>=8
    // out k-index = sh*9 + sw4. Active lanes per (rg,sh,tile) write 4
    // contiguous 36B runs (one per kq) -> merged to full lines in L2.
    // LeakyReLU as fmaxf(v, 0.1v): identical result, 1 fewer VALU op.
    const float sc = 1.0f / (float)Cn;
    const size_t rowbase = ((size_t)((b * Hh + h0 + wv) * Ww) + w0) * 81;
#pragma unroll
    for (int rg = 0; rg < 4; ++rg) {
        int m = kq * 4 + rg;
        int d = nI - m;
        bool t0 = (d >= 0 && d <= 8);
        bool t1 = (d >= -8 && d <= 0 && nI >= 8);
        size_t mb = rowbase + (size_t)m * 81;
#pragma unroll
        for (int sh = 0; sh < 9; ++sh) {
            if (t0) {
                float v = ac0[sh][rg] * sc;
                out[mb + sh * 9 + d] = fmaxf(v, NEG * v);
            }
            if (t1) {
                float v = ac1[sh][rg] * sc;
                out[mb + sh * 9 + d + 8] = fmaxf(v, NEG * v);
            }
        }
    }
}

extern "C" void kernel_launch(void* const* d_in, const int* in_sizes, int n_in,
                              void* d_out, int out_size, void* d_ws, size_t ws_size,
                              hipStream_t stream) {
    const float* x1 = (const float*)d_in[0];
    const float* wp = (const float*)d_in[1];
    float* out = (float*)d_out;
    dim3 grid(12 * 16 * 8, 1, 1);   // 1536 blocks, XCD-swizzled in-kernel
    costvol_mfma<<<grid, NTHR, 0, stream>>>(x1, wp, out);
}

// Round 14
// 55.250 us; speedup vs baseline: 1.0704x; 1.0306x over previous
//
#include <hip/hip_runtime.h>

// CostVolume via banded-correlation MFMA (v_mfma_f32_16x16x32_f16).
// cost[b,h,w,(sh+4)*9+(sw+4)] = LeakyReLU_0.1( mean_c x1[b,h,w,c]*warped[b,h+sh,w+sw,c] )
// B=8 H=128 W=192 C=128, MD=4. Output fp32 [B,H,W,81].
//
// Round-14: R11 (55.3us champion) + kq-plane BANK STAGGER (KQB 384->400).
// R13 lesson: setprio HURTS this lockstep 8-wave structure (+1.6us,
// matching learn_hip m190's GEMM result) -- removed.
// Conflict theory: SQ_LDS_BANK_CONFLICT = 4.42M over ~1.03M b128 LDS ops
// (+4.3 cy/op). Cause: kq planes at kq*384, and 384 === 0 mod 128B -> for
// matching slot v, the 4 lanes (one per kq group) hit the SAME 4-bank span
// -> 4-way alignment collision (m136: 1.58x). Padding KQB to 400B makes
// kq*100 dwords === kq*4 mod 32: each plane staggers 4 banks, same-v
// accesses across kq land on disjoint spans; worst case drops to the free
// 2-way (v vs v+8 within a group). Rows stagger too (1600B === 16 banks).
// Correctness unchanged: b1 = ro0+128 identity depends only on the
// (nI^(kq<<1))*16 term; slot index < 24 so the 16B pad is never touched.
// LDS 2x25600 = 51200B <= 64K static; 160K/50K -> still 3 blocks/CU.
// Also kept: fmaxf(v, 0.1v) LeakyReLU (provably identical, -1 VALU op).
//
// Structure (= R11): 8x16 tile, 8 waves; dual staging sets gpA/gpB --
// c0,c1 issued back-to-back in prologue, c2 before loop, c3 at step0;
// load->commit distance >= 1.5-2 steps, two 49KB bursts in flight.
// RH=16 swizzled staging, lgkm-only barriers, XCD swizzle (192 wg = one
// image per XCD), rolling x1 raw prefetch, direct band stores.

namespace {
constexpr int Bb = 8, Hh = 128, Ww = 192, Cn = 128;
constexpr int MDc = 4;
constexpr int TH = 8, TWT = 16;        // block tile: 8 rows x 16 px
constexpr int NTHR = 512;              // 8 waves
constexpr int RH = 16;                 // staged warped rows  (h0-4 .. h0+11)
constexpr int RPX = 24;                // staged warped px    (w0-4 .. w0+19)
constexpr int KC = 32;                 // channels per chunk
constexpr int NCH = Cn / KC;           // 4
constexpr int KQB = RPX * 16 + 16;     // 400 B per kq-plane (24 slots + 16B pad)
constexpr int ROWB = 4 * KQB;          // 1600 B per staged row
constexpr int BUFB = RH * ROWB;        // 25600 B per buffer
constexpr int RUNS = RH * RPX * 4;     // 1536 8-channel runs per chunk
constexpr int NIT = RUNS / NTHR;       // 3
constexpr float NEG = 0.1f;
}

typedef __fp16 h2v   __attribute__((ext_vector_type(2)));
typedef __fp16 f16x8 __attribute__((ext_vector_type(8)));
typedef float  f32x4 __attribute__((ext_vector_type(4)));

__device__ __forceinline__ unsigned pkh2(float a, float b) {
    h2v h = __builtin_amdgcn_cvt_pkrtz(a, b);
    return __builtin_bit_cast(unsigned, h);
}

// Barrier with LDS-only drain: global prefetch loads stay in flight across it.
__device__ __forceinline__ void barrier_lgkm() {
    asm volatile("s_waitcnt lgkmcnt(0)\n\ts_barrier" ::: "memory");
}

__global__ __launch_bounds__(NTHR, 4)
void costvol_mfma(const float* __restrict__ x1,
                  const float* __restrict__ wp,
                  float* __restrict__ out)
{
    __shared__ __align__(16) unsigned char smem[2 * BUFB];   // 51200 B

    const int tid  = threadIdx.x;
    const int wv   = tid >> 6;        // 0..7 : h-row within stripe
    const int lane = tid & 63;
    const int nI   = lane & 15;       // A-row m / B-col n lane index
    const int kq   = lane >> 4;       // 0..3 : k-group (8 channels each)

    // XCD swizzle: 1536 wg = 8 XCDs x 192; 192 = one batch image (12x16).
    const int id = blockIdx.x;
    const int wg = (id & 7) * 192 + (id >> 3);
    const int bx = wg % 12;
    const int t2 = wg / 12;
    const int by = t2 & 15;
    const int bz = t2 >> 4;

    const int w0 = bx * TWT;
    const int h0 = by * TH;
    const int b  = bz;

    // ---- warped staging decode: run = (row, px, kq), kq innermost ----
    int g_off[NIT]; int l_off[NIT]; bool g_ok[NIT];
#pragma unroll
    for (int it = 0; it < NIT; ++it) {
        int s   = tid + it * NTHR;    // 0..1535
        int skq = s & 3;
        int t   = s >> 2;             // 0..383
        int px  = t % RPX;
        int row = t / RPX;
        int hw  = h0 - MDc + row;
        int ww  = w0 - MDc + px;
        bool ok = (unsigned)hw < (unsigned)Hh && (unsigned)ww < (unsigned)Ww;
        g_ok[it]  = ok;
        g_off[it] = ((b * Hh + (ok ? hw : 0)) * Ww + (ok ? ww : 0)) * Cn + skq * 8;
        l_off[it] = row * ROWB + skq * KQB + ((px ^ (skq << 1)) * 16);
    }

    // Two independent staging register sets: A = even chunks, B = odd.
    uint4 gpA[NIT], gpB[NIT];
    auto LOADA = [&](int ch) {
#pragma unroll
        for (int it = 0; it < NIT; ++it) {
            if (g_ok[it]) {
                const float* p = wp + g_off[it] + ch * KC;
                float4 u = *reinterpret_cast<const float4*>(p);
                float4 v = *reinterpret_cast<const float4*>(p + 4);
                gpA[it] = make_uint4(pkh2(u.x, u.y), pkh2(u.z, u.w),
                                     pkh2(v.x, v.y), pkh2(v.z, v.w));
            } else {
                gpA[it] = make_uint4(0u, 0u, 0u, 0u);
            }
        }
    };
    auto LOADB = [&](int ch) {
#pragma unroll
        for (int it = 0; it < NIT; ++it) {
            if (g_ok[it]) {
                const float* p = wp + g_off[it] + ch * KC;
                float4 u = *reinterpret_cast<const float4*>(p);
                float4 v = *reinterpret_cast<const float4*>(p + 4);
                gpB[it] = make_uint4(pkh2(u.x, u.y), pkh2(u.z, u.w),
                                     pkh2(v.x, v.y), pkh2(v.z, v.w));
            } else {
                gpB[it] = make_uint4(0u, 0u, 0u, 0u);
            }
        }
    };
    auto WRITEA = [&](int buf) {
#pragma unroll
        for (int it = 0; it < NIT; ++it)
            *reinterpret_cast<uint4*>(smem + buf * BUFB + l_off[it]) = gpA[it];
    };
    auto WRITEB = [&](int buf) {
#pragma unroll
        for (int it = 0; it < NIT; ++it)
            *reinterpret_cast<uint4*>(smem + buf * BUFB + l_off[it]) = gpB[it];
    };

    // ---- prologue: issue c0,c1 back-to-back, then x1, commit c0, issue c2.
    LOADA(0);
    LOADB(1);

    const float* xp = x1 + ((size_t)((b * Hh + h0 + wv) * Ww) + w0 + nI) * Cn + kq * 8;
    float4 ar_u = *reinterpret_cast<const float4*>(xp);
    float4 ar_v = *reinterpret_cast<const float4*>(xp + 4);

    f32x4 ac0[9], ac1[9];
#pragma unroll
    for (int s = 0; s < 9; ++s) {
        f32x4 z = {0.f, 0.f, 0.f, 0.f};
        ac0[s] = z; ac1[s] = z;
    }

    // per-lane B fragment offset within a staged row; tile1 = ro0 + 128
    // (identity: ((nI+8)^(kq<<1))*16 == (nI^(kq<<1))*16 + 128, KQB-independent)
    const int ro0 = kq * KQB + ((nI ^ (kq << 1)) * 16);

    WRITEA(0);       // commit c0 -> buf0 (waits only on gpA's loads)
    LOADA(2);        // c2 in flight across steps 0..1

    int cur = 0;
#pragma unroll
    for (int ch = 0; ch < NCH; ++ch) {
        barrier_lgkm();
        // commit chunk ch+1 into the other buffer; issue chunk ch+3
        if (ch == 0) { WRITEB(1); LOADB(3); }   // c1 -> buf1; c3 spans steps 0..2
        if (ch == 1) { WRITEA(0); }             // c2 -> buf0
        if (ch == 2) { WRITEB(1); }             // c3 -> buf1
        // x1: convert this chunk (loaded last step), issue next chunk
        uint4 afr = make_uint4(pkh2(ar_u.x, ar_u.y), pkh2(ar_u.z, ar_u.w),
                               pkh2(ar_v.x, ar_v.y), pkh2(ar_v.z, ar_v.w));
        if (ch + 1 < NCH) {
            ar_u = *reinterpret_cast<const float4*>(xp + (ch + 1) * KC);
            ar_v = *reinterpret_cast<const float4*>(xp + (ch + 1) * KC + 4);
        }
        f16x8 av = __builtin_bit_cast(f16x8, afr);
        const unsigned char* base = smem + cur * BUFB;
#pragma unroll
        for (int sh = 0; sh < 9; ++sh) {
            const unsigned char* rp = base + (wv + sh) * ROWB;   // staged row ly+sh
            uint4 b0 = *reinterpret_cast<const uint4*>(rp + ro0);
            uint4 b1 = *reinterpret_cast<const uint4*>(rp + ro0 + 128);
            ac0[sh] = __builtin_amdgcn_mfma_f32_16x16x32_f16(
                av, __builtin_bit_cast(f16x8, b0), ac0[sh], 0, 0, 0);
            ac1[sh] = __builtin_amdgcn_mfma_f32_16x16x32_f16(
                av, __builtin_bit_cast(f16x8, b1), ac1[sh], 0, 0, 0);
        }
        cur ^= 1;
    }

    // ---- direct band stores: no LDS round-trip, no barriers ----
    // C/D map: col=n=lane&15, row=m=(lane>>4)*4+reg
    // tile0: staged px p = nI      -> (m, sw4 = nI-m),   valid d=nI-m in [0,8]
    // tile1: staged px p = nI + 8  -> (m, sw4 = nI-m+8), valid d in [-8,0] && nI>=8
    // out k-index = sh*9 + sw4. Active lanes per (rg,sh,tile) write 4
    // contiguous 36B runs (one per kq) -> merged to full lines in L2.
    // LeakyReLU as fmaxf(v, 0.1v): identical result, 1 fewer VALU op.
    const float sc = 1.0f / (float)Cn;
    const size_t rowbase = ((size_t)((b * Hh + h0 + wv) * Ww) + w0) * 81;
#pragma unroll
    for (int rg = 0; rg < 4; ++rg) {
        int m = kq * 4 + rg;
        int d = nI - m;
        bool t0 = (d >= 0 && d <= 8);
        bool t1 = (d >= -8 && d <= 0 && nI >= 8);
        size_t mb = rowbase + (size_t)m * 81;
#pragma unroll
        for (int sh = 0; sh < 9; ++sh) {
            if (t0) {
                float v = ac0[sh][rg] * sc;
                out[mb + sh * 9 + d] = fmaxf(v, NEG * v);
            }
            if (t1) {
                float v = ac1[sh][rg] * sc;
                out[mb + sh * 9 + d + 8] = fmaxf(v, NEG * v);
            }
        }
    }
}

extern "C" void kernel_launch(void* const* d_in, const int* in_sizes, int n_in,
                              void* d_out, int out_size, void* d_ws, size_t ws_size,
                              hipStream_t stream) {
    const float* x1 = (const float*)d_in[0];
    const float* wp = (const float*)d_in[1];
    float* out = (float*)d_out;
    dim3 grid(12 * 16 * 8, 1, 1);   // 1536 blocks, XCD-swizzled in-kernel
    costvol_mfma<<<grid, NTHR, 0, stream>>>(x1, wp, out);
}